// Round 4
// baseline (610.427 us; speedup 1.0000x reference)
//
#include <hip/hip_runtime.h>
#include <hip/hip_bf16.h>

// MetaUpscale: out[n,o,oy,ox] = sum_{ch<576} patch[n][oy/2][ox/2][ch] * lw[oy][ox][ch][o]
// patch[n][hy][wx][c*9 + kh*3 + kw] = x[n][c][hy+kh-1][wx+kw-1] (zero pad)
// N=2, C=64, H=W=128, S=2 -> out (2,3,256,256). All tensors FP32 (per reference).
//
// Structure (R4): software-pipelined. Each wave issues ALL 27 coalesced lw
// loads for its output pixel up front (no LDS dependence), then the block
// stages the shared 3x3xC patch into LDS, then the FMA loop consumes the
// loads as they land. lw is streamed flat (e = k*64+lane, stride-4
// coalesced); since 64 == 1 (mod 3), o = e%3 = (k+lane)%3, so we accumulate
// into acc[k%3] (static index) and rotate by lane%3 once at the end.

namespace {

constexpr int N_    = 2;
constexpr int C_    = 64;
constexpr int H_    = 128;
constexpr int W_    = 128;
constexpr int CH9   = C_ * 9;    // 576
constexpr int CHUNK = CH9 * 3;   // 1728 floats of lw per output pixel
constexpr int OH    = 256;
constexpr int OW    = 256;
constexpr int KITER = 27;        // 1728 / 64

__global__ __launch_bounds__(256)
void metaupscale_kernel(const float* __restrict__ x,
                        const float* __restrict__ lw,
                        float* __restrict__ out) {
    __shared__ float patch[N_ * CH9];   // [n][ch], 4.6 KB

    const int blk = blockIdx.x;         // one input pixel per block
    const int hy  = blk / W_;
    const int wx  = blk - hy * W_;
    const int tid = threadIdx.x;

    const int wave = tid >> 6;          // 0..3 -> output sub-pixel
    const int lane = tid & 63;
    const int sy   = wave >> 1;
    const int sx   = wave & 1;
    const int oy   = hy * 2 + sy;
    const int ox   = wx * 2 + sx;

    // ---- Phase 1: issue all lw loads up front (independent of LDS) ----
    const float* __restrict__ lwp =
        lw + (size_t)(oy * OW + ox) * CHUNK + lane;
    float w[KITER];
    #pragma unroll
    for (int k = 0; k < KITER; ++k) {
        w[k] = lwp[k * 64];             // stride-4 coalesced across the wave
    }

    // ---- Phase 2: stage the 3x3xC patch for both batch images into LDS ----
    for (int e = tid; e < N_ * CH9; e += 256) {
        const int n  = e / CH9;
        const int ch = e - n * CH9;
        const int c  = ch / 9;
        const int j  = ch - c * 9;
        const int h  = hy + (j / 3) - 1;
        const int ww = wx + (j % 3) - 1;
        float v = 0.0f;
        if ((unsigned)h < (unsigned)H_ && (unsigned)ww < (unsigned)W_) {
            v = x[((n * C_ + c) * H_ + h) * W_ + ww];
        }
        patch[e] = v;
    }
    __syncthreads();

    // ---- Phase 3: consume. ch = (k*64+lane)/3 = 21k + k/3 + (lane+k%3)/3 ----
    const int d0 = lane / 3;            // (lane+0)/3
    const int d1 = (lane + 1) / 3;
    const int d2 = (lane + 2) / 3;

    float acc[N_][3] = {};              // acc[n][k%3]; true o = (k%3 + lane%3)%3

    #pragma unroll
    for (int k = 0; k < KITER; ++k) {
        const int km = k % 3;           // compile-time
        const int ch = 21 * k + k / 3 + (km == 0 ? d0 : km == 1 ? d1 : d2);
        const float p0 = patch[ch];
        const float p1 = patch[CH9 + ch];
        acc[0][km] += p0 * w[k];
        acc[1][km] += p1 * w[k];
    }

    // ---- Rotate m -> true o per lane: o = (m + r) % 3, r = lane % 3 ----
    const int r = lane % 3;
    float racc[N_][3];
    #pragma unroll
    for (int n = 0; n < N_; ++n) {
        #pragma unroll
        for (int o = 0; o < 3; ++o) {
            const int m = (o - r + 3) % 3;
            racc[n][o] = (m == 0) ? acc[n][0] : (m == 1) ? acc[n][1] : acc[n][2];
        }
    }

    // ---- Wave reduction ----
    #pragma unroll
    for (int off = 32; off > 0; off >>= 1) {
        #pragma unroll
        for (int n = 0; n < N_; ++n) {
            #pragma unroll
            for (int o = 0; o < 3; ++o) {
                racc[n][o] += __shfl_down(racc[n][o], off, 64);
            }
        }
    }

    if (lane == 0) {
        #pragma unroll
        for (int n = 0; n < N_; ++n) {
            #pragma unroll
            for (int o = 0; o < 3; ++o) {
                out[(((size_t)n * 3 + o) * OH + oy) * OW + ox] = racc[n][o];
            }
        }
    }
}

}  // namespace

extern "C" void kernel_launch(void* const* d_in, const int* in_sizes, int n_in,
                              void* d_out, int out_size, void* d_ws, size_t ws_size,
                              hipStream_t stream) {
    const float* x  = (const float*)d_in[0];
    const float* lw = (const float*)d_in[1];
    // d_in[2] = scale (int32, ==2) — compile-time constant here.
    float* out = (float*)d_out;

    const int grid = H_ * W_;   // 16384 blocks, one per input pixel
    metaupscale_kernel<<<grid, 256, 0, stream>>>(x, lw, out);
}